// Round 10
// baseline (558.860 us; speedup 1.0000x reference)
//
#include <hip/hip_runtime.h>
#include <hip/hip_fp16.h>

#define NN 50000
#define DD 128
#define NE 800000
#define BN_EPS 1e-5f

// ---------------- CSR build ----------------
__global__ void k_hist(const int* __restrict__ dst, int* __restrict__ cnt, int ne) {
    int i = blockIdx.x * blockDim.x + threadIdx.x;
    if (i < ne) atomicAdd(&cnt[dst[i]], 1);
}

__global__ __launch_bounds__(256) void k_bsum(const int* __restrict__ cnt,
                                              int* __restrict__ bsum, int n) {
    __shared__ int red[256];
    int i = blockIdx.x * 256 + threadIdx.x;
    int v = (i < n) ? cnt[i] : 0;
    red[threadIdx.x] = v;
    __syncthreads();
    for (int off = 128; off > 0; off >>= 1) {
        if (threadIdx.x < off) red[threadIdx.x] += red[threadIdx.x + off];
        __syncthreads();
    }
    if (threadIdx.x == 0) bsum[blockIdx.x] = red[0];
}

__global__ __launch_bounds__(256) void k_bscan(int* __restrict__ bsum, int nb) {
    __shared__ int sh[256];
    int t = threadIdx.x;
    sh[t] = (t < nb) ? bsum[t] : 0;
    __syncthreads();
    for (int off = 1; off < 256; off <<= 1) {
        int add = (t >= off) ? sh[t - off] : 0;
        __syncthreads();
        sh[t] += add;
        __syncthreads();
    }
    if (t < nb) bsum[t] = sh[t];
}

// writes rowp/dinv + coarse-bucket cursors (64-node buckets); block 0 zeroes sums+Zb.
__global__ __launch_bounds__(256) void k_rowp(const int* __restrict__ cnt,
                                              const int* __restrict__ bsum,
                                              int* __restrict__ rowp,
                                              int* __restrict__ ccur,
                                              float* __restrict__ dinv,
                                              float* __restrict__ sumsZ, int n) {
    if (blockIdx.x == 0) {
        for (int i = threadIdx.x; i < 4160; i += 256) sumsZ[i] = 0.f;
    }
    __shared__ int sh[256];
    int t = threadIdx.x;
    int i = blockIdx.x * 256 + t;
    int v = (i < n) ? cnt[i] : 0;
    sh[t] = v;
    __syncthreads();
    for (int off = 1; off < 256; off <<= 1) {
        int add = (t >= off) ? sh[t - off] : 0;
        __syncthreads();
        sh[t] += add;
        __syncthreads();
    }
    int base = (blockIdx.x > 0) ? bsum[blockIdx.x - 1] : 0;
    int excl = base + sh[t] - v;
    if (i < n) {
        rowp[i] = excl;
        if ((i & 63) == 0) ccur[i >> 6] = excl;   // bucket base cursor
        dinv[i] = 1.0f / sqrtf((float)(v + 1));
        if (i == n - 1) rowp[n] = excl + v;
    }
}

// Pass A: coarse-bin edges into bucket-contiguous tmp (packed int2 record).
__global__ void k_binA(const int* __restrict__ src, const int* __restrict__ dst,
                       int* __restrict__ ccur, int2* __restrict__ tmp, int ne) {
    int i = blockIdx.x * blockDim.x + threadIdx.x;
    if (i < ne) {
        int d = dst[i], s = src[i];
        int pos = atomicAdd(&ccur[d >> 6], 1);
        tmp[pos] = make_int2(s, d);
    }
}

// Pass B: one block per 64-node bucket; LDS per-node cursors; block-private
// write window (~8 KB) -> full-line writebacks.
__global__ __launch_bounds__(256) void k_binB(const int2* __restrict__ tmp,
                                              const int* __restrict__ rowp,
                                              const float* __restrict__ dinv,
                                              int* __restrict__ col,
                                              float* __restrict__ val, int n) {
    __shared__ int cur[64];
    int node0 = blockIdx.x << 6;
    if (threadIdx.x < 64) {
        int node = node0 + threadIdx.x;
        cur[threadIdx.x] = (node < n) ? rowp[node] : 0;
    }
    __syncthreads();
    int base = rowp[node0];
    int top = rowp[min(node0 + 64, n)];
    for (int j = base + (int)threadIdx.x; j < top; j += 256) {
        int2 r = tmp[j];
        int pos = atomicAdd(&cur[r.y & 63], 1);
        col[pos] = r.x;
        val[pos] = dinv[r.x];
    }
}

// ---------------- GEMM: persistent blocks, fp16 output table ----------------
#define GROWS 32
#define GEMM_BLOCKS 512
__global__ __launch_bounds__(256) void k_gemm(const float* __restrict__ A,
                                              const float* __restrict__ W,
                                              __half* __restrict__ C, int n) {
    __shared__ float sA[GROWS][DD];
    __shared__ float sW[DD][DD];
    int tid = threadIdx.x;

    {
        const float4* Wv = (const float4*)W;
        float4* sWv = (float4*)&sW[0][0];
        for (int i = tid; i < DD * DD / 4; i += 256) sWv[i] = Wv[i];
    }

    int ntiles = (n + GROWS - 1) / GROWS;
    int tx = tid & 31;
    int ty = tid >> 5;
    for (int t = blockIdx.x; t < ntiles; t += gridDim.x) {
        int row0 = t * GROWS;
        __syncthreads();
        {
            const float4* Av = (const float4*)(A + (size_t)row0 * DD);
            float4* sAv = (float4*)&sA[0][0];
            for (int i = tid; i < GROWS * DD / 4; i += 256) {
                int r = i >> 5;
                float4 v = make_float4(0.f, 0.f, 0.f, 0.f);
                if (row0 + r < n) v = Av[i];
                sAv[i] = v;
            }
        }
        __syncthreads();

        float acc[4][4] = {};
        for (int k = 0; k < DD; k += 4) {
            float a[4][4], b[4][4];
            #pragma unroll
            for (int r = 0; r < 4; r++)
                *(float4*)a[r] = *(const float4*)&sA[ty * 4 + r][k];
            #pragma unroll
            for (int kk = 0; kk < 4; kk++)
                *(float4*)b[kk] = *(const float4*)&sW[k + kk][tx * 4];
            #pragma unroll
            for (int r = 0; r < 4; r++)
                #pragma unroll
                for (int kk = 0; kk < 4; kk++)
                    #pragma unroll
                    for (int c = 0; c < 4; c++)
                        acc[r][c] += a[r][kk] * b[kk][c];
        }
        #pragma unroll
        for (int r = 0; r < 4; r++) {
            int row = row0 + ty * 4 + r;
            if (row < n) {
                __half2 p0 = __floats2half2_rn(acc[r][0], acc[r][1]);
                __half2 p1 = __floats2half2_rn(acc[r][2], acc[r][3]);
                uint2 pk;
                pk.x = *(unsigned int*)&p0;
                pk.y = *(unsigned int*)&p1;
                *(uint2*)(C + (size_t)row * DD + tx * 4) = pk;
            }
        }
    }
}

// ---------------- aggregation: one wave/node, fp16 gather, fused BN stats ----------
__global__ __launch_bounds__(256) void k_agg(const __half* __restrict__ h,
                                             const int* __restrict__ rowp,
                                             const int* __restrict__ col,
                                             const float* __restrict__ val,
                                             const float* __restrict__ dinv,
                                             const float* __restrict__ bias,
                                             float* __restrict__ out,
                                             float* __restrict__ sums, int n) {
    int tid = threadIdx.x;
    int w = tid >> 6;              // wave 0..3
    int lane = tid & 63;
    int g = lane >> 4;             // edge group 0..3
    int m = lane & 15;             // 16 B chunk within row
    int node = blockIdx.x * 4 + w;
    bool activ = node < n;

    float a[8] = {0.f, 0.f, 0.f, 0.f, 0.f, 0.f, 0.f, 0.f};
    int beg = 0, end = 0;
    if (activ) { beg = rowp[node]; end = rowp[node + 1]; }
    #pragma unroll 4
    for (int e = beg + g; e < end; e += 4) {
        int s = col[e];
        float ww = val[e];
        float4 raw = *(const float4*)(h + (size_t)s * DD + m * 8);
        const __half2* hp = (const __half2*)&raw;
        float2 c0 = __half22float2(hp[0]);
        float2 c1 = __half22float2(hp[1]);
        float2 c2 = __half22float2(hp[2]);
        float2 c3 = __half22float2(hp[3]);
        a[0] += ww * c0.x; a[1] += ww * c0.y;
        a[2] += ww * c1.x; a[3] += ww * c1.y;
        a[4] += ww * c2.x; a[5] += ww * c2.y;
        a[6] += ww * c3.x; a[7] += ww * c3.y;
    }
    #pragma unroll
    for (int j = 0; j < 8; j++) {
        a[j] += __shfl_xor(a[j], 16);
        a[j] += __shfl_xor(a[j], 32);
    }
    float o[8] = {0.f, 0.f, 0.f, 0.f, 0.f, 0.f, 0.f, 0.f};
    if (activ && lane < 16) {
        float di = dinv[node], dii = di * di;
        float4 raw = *(const float4*)(h + (size_t)node * DD + m * 8);
        const __half2* hp = (const __half2*)&raw;
        float2 s0 = __half22float2(hp[0]);
        float2 s1 = __half22float2(hp[1]);
        float2 s2 = __half22float2(hp[2]);
        float2 s3 = __half22float2(hp[3]);
        float sf[8] = {s0.x, s0.y, s1.x, s1.y, s2.x, s2.y, s3.x, s3.y};
        float4 b0 = *(const float4*)(bias + m * 8);
        float4 b1 = *(const float4*)(bias + m * 8 + 4);
        float bf[8] = {b0.x, b0.y, b0.z, b0.w, b1.x, b1.y, b1.z, b1.w};
        #pragma unroll
        for (int j = 0; j < 8; j++)
            o[j] = di * a[j] + dii * sf[j] + bf[j];
        float* op = out + (size_t)node * DD + m * 8;
        *(float4*)op = make_float4(o[0], o[1], o[2], o[3]);
        *(float4*)(op + 4) = make_float4(o[4], o[5], o[6], o[7]);
    }
    __shared__ float rs[4][128];
    __shared__ float rq[4][128];
    if (lane < 16) {
        #pragma unroll
        for (int j = 0; j < 8; j++) {
            rs[w][m * 8 + j] = o[j];
            rq[w][m * 8 + j] = o[j] * o[j];
        }
    }
    __syncthreads();
    int bank = blockIdx.x & 7;
    if (tid < 128) {
        float s = rs[0][tid] + rs[1][tid] + rs[2][tid] + rs[3][tid];
        atomicAdd(&sums[bank * 256 + tid], s);
    } else {
        int t = tid - 128;
        float q = rq[0][t] + rq[1][t] + rq[2][t] + rq[3][t];
        atomicAdd(&sums[bank * 256 + 128 + t], q);
    }
}

// ---------------- BN apply + ReLU + residual, optional fused attention score --------
__global__ __launch_bounds__(256) void k_bn(const float* __restrict__ X,
                                            const float* __restrict__ res,
                                            const float* __restrict__ sums,
                                            const float* __restrict__ gamma,
                                            const float* __restrict__ beta,
                                            const float* __restrict__ Wa,
                                            const float* __restrict__ ba,
                                            float* __restrict__ out,
                                            float* __restrict__ evec,
                                            float* __restrict__ Zb, int n) {
    __shared__ float s_scale[128], s_shift[128];
    if (threadIdx.x < 128) {
        int ff = threadIdx.x;
        float ssum = 0.f, qsum = 0.f;
        #pragma unroll
        for (int b = 0; b < 8; b++) {
            ssum += sums[b * 256 + ff];
            qsum += sums[b * 256 + 128 + ff];
        }
        float inv_n = 1.0f / (float)n;
        float mean = ssum * inv_n;
        float var = qsum * inv_n - mean * mean;
        float sc = gamma[ff] * (1.0f / sqrtf(var + BN_EPS));
        s_scale[ff] = sc;
        s_shift[ff] = beta[ff] - mean * sc;
    }
    __syncthreads();
    int idx = blockIdx.x * 256 + threadIdx.x;
    int total = n * (DD / 4);
    int f = (threadIdx.x & 31) * 4;
    float o[4] = {0.f, 0.f, 0.f, 0.f};
    if (idx < total) {
        float4 v = ((const float4*)X)[idx];
        float4 rv = ((const float4*)res)[idx];
        float vi[4] = {v.x, v.y, v.z, v.w};
        float ri[4] = {rv.x, rv.y, rv.z, rv.w};
        #pragma unroll
        for (int j = 0; j < 4; j++) {
            float x = vi[j] * s_scale[f + j] + s_shift[f + j];
            x = fmaxf(x, 0.f);
            o[j] = x + ri[j];
        }
        ((float4*)out)[idx] = make_float4(o[0], o[1], o[2], o[3]);
    }
    if (Wa != nullptr) {
        float t = 0.f;
        if (idx < total) {
            float4 wv = *(const float4*)(Wa + f);
            t = o[0] * wv.x + o[1] * wv.y + o[2] * wv.z + o[3] * wv.w;
        }
        #pragma unroll
        for (int m = 16; m >= 1; m >>= 1) t += __shfl_xor(t, m);
        __shared__ float part[8];
        if ((threadIdx.x & 31) == 0) {
            float ev = 0.f;
            if (idx < total) {
                ev = expf(tanhf(t + ba[0]));
                evec[idx >> 5] = ev;
            }
            part[threadIdx.x >> 5] = ev;
        }
        __syncthreads();
        if (threadIdx.x == 0) {
            float z = part[0] + part[1] + part[2] + part[3] +
                      part[4] + part[5] + part[6] + part[7];
            atomicAdd(&Zb[blockIdx.x & 63], z);
        }
    }
}

// ---------------- final: out = h * e / Z (Z from 64 banks) ----------------
__global__ __launch_bounds__(256) void k_out(const float* __restrict__ H,
                                             const float* __restrict__ evec,
                                             const float* __restrict__ Zb,
                                             float* __restrict__ out, int n) {
    __shared__ float sZ;
    if (threadIdx.x == 0) {
        float z = 0.f;
        #pragma unroll
        for (int i = 0; i < 64; i++) z += Zb[i];
        sZ = z;
    }
    __syncthreads();
    int idx = blockIdx.x * blockDim.x + threadIdx.x;
    int total = n * (DD / 4);
    if (idx >= total) return;
    int node = idx >> 5;
    float s = evec[node] / sZ;
    float4 h = ((const float4*)H)[idx];
    ((float4*)out)[idx] = make_float4(h.x * s, h.y * s, h.z * s, h.w * s);
}

extern "C" void kernel_launch(void* const* d_in, const int* in_sizes, int n_in,
                              void* d_out, int out_size, void* d_ws, size_t ws_size,
                              hipStream_t stream) {
    const float* x   = (const float*)d_in[0];
    const int* eidx  = (const int*)d_in[1];
    const float* W1  = (const float*)d_in[2];
    const float* b1  = (const float*)d_in[3];
    const float* g1  = (const float*)d_in[4];
    const float* be1 = (const float*)d_in[5];
    const float* W2  = (const float*)d_in[6];
    const float* b2  = (const float*)d_in[7];
    const float* g2  = (const float*)d_in[8];
    const float* be2 = (const float*)d_in[9];
    const float* Wa  = (const float*)d_in[10];
    const float* ba  = (const float*)d_in[11];
    float* out = (float*)d_out;

    const int* srcp = eidx;
    const int* dstp = eidx + NE;

    float* bufA = (float*)d_ws;              // N*D region; fp16 gather table
    float* bufB = bufA + (size_t)NN * DD;    // N*D (agg out; tmp overlay in build)
    float* bufC = bufB + (size_t)NN * DD;    // N*D (h1 / h2)
    float* val  = bufC + (size_t)NN * DD;    // NE
    float* dinv = val + NE;                  // NN
    float* evec = dinv + NN;                 // NN
    float* sums = evec + NN;                 // 2 layers x 8 banks x 256 = 4096
    float* Zb   = sums + 4096;               // 64 banks
    int* cnt    = (int*)(Zb + 64);           // NN
    int* rowp   = cnt + NN;                  // NN+1 (pad 64)
    int* ccur   = rowp + NN + 64;            // 782 coarse cursors (pad 1024)
    int* col    = ccur + 1024;               // NE
    int* bsum   = col + NE;                  // 256

    __half* hH  = (__half*)bufA;             // fp16 gather table, 12.8 MB
    int2* tmp   = (int2*)bufB;               // 6.4 MB edge records (build only)

    float* sumsL1 = sums;
    float* sumsL2 = sums + 2048;

    const int nscan = (NN + 255) / 256;      // 196 blocks
    const int nbuck = (NN + 63) / 64;        // 782 buckets

    // ---- CSR build (k_rowp block 0 zeroes sums+Zb) ----
    hipMemsetAsync(cnt, 0, (size_t)NN * sizeof(int), stream);
    k_hist<<<(NE + 255) / 256, 256, 0, stream>>>(dstp, cnt, NE);
    k_bsum<<<nscan, 256, 0, stream>>>(cnt, bsum, NN);
    k_bscan<<<1, 256, 0, stream>>>(bsum, nscan);
    k_rowp<<<nscan, 256, 0, stream>>>(cnt, bsum, rowp, ccur, dinv, sums, NN);
    k_binA<<<(NE + 255) / 256, 256, 0, stream>>>(srcp, dstp, ccur, tmp, NE);
    k_binB<<<nbuck, 256, 0, stream>>>(tmp, rowp, dinv, col, val, NN);

    int agg_grid  = (NN + 3) / 4;                    // 12500
    int ew_grid   = (NN * (DD / 4) + 255) / 256;     // 6250

    // ---- layer 1 ----
    k_gemm<<<GEMM_BLOCKS, 256, 0, stream>>>(x, W1, hH, NN);
    k_agg<<<agg_grid, 256, 0, stream>>>(hH, rowp, col, val, dinv, b1, bufB, sumsL1, NN);
    k_bn<<<ew_grid, 256, 0, stream>>>(bufB, x, sumsL1, g1, be1, nullptr, nullptr,
                                      bufC, nullptr, nullptr, NN);

    // ---- layer 2 ----
    k_gemm<<<GEMM_BLOCKS, 256, 0, stream>>>(bufC, W2, hH, NN);
    k_agg<<<agg_grid, 256, 0, stream>>>(hH, rowp, col, val, dinv, b2, bufB, sumsL2, NN);
    k_bn<<<ew_grid, 256, 0, stream>>>(bufB, bufC, sumsL2, g2, be2, Wa, ba,
                                      bufC, evec, Zb, NN);   // in-place res ok

    // ---- output ----
    k_out<<<ew_grid, 256, 0, stream>>>(bufC, evec, Zb, out, NN);
}

// Round 11
// 406.303 us; speedup vs baseline: 1.3755x; 1.3755x over previous
//
#include <hip/hip_runtime.h>
#include <hip/hip_fp16.h>

#define NN 50000
#define DD 128
#define NE 800000
#define BN_EPS 1e-5f

// ---------------- CSR build ----------------
__global__ void k_hist(const int* __restrict__ dst, int* __restrict__ cnt, int ne) {
    int i = blockIdx.x * blockDim.x + threadIdx.x;
    if (i < ne) atomicAdd(&cnt[dst[i]], 1);
}

__global__ __launch_bounds__(256) void k_bsum(const int* __restrict__ cnt,
                                              int* __restrict__ bsum, int n) {
    __shared__ int red[256];
    int i = blockIdx.x * 256 + threadIdx.x;
    int v = (i < n) ? cnt[i] : 0;
    red[threadIdx.x] = v;
    __syncthreads();
    for (int off = 128; off > 0; off >>= 1) {
        if (threadIdx.x < off) red[threadIdx.x] += red[threadIdx.x + off];
        __syncthreads();
    }
    if (threadIdx.x == 0) bsum[blockIdx.x] = red[0];
}

__global__ __launch_bounds__(256) void k_bscan(int* __restrict__ bsum, int nb) {
    __shared__ int sh[256];
    int t = threadIdx.x;
    sh[t] = (t < nb) ? bsum[t] : 0;
    __syncthreads();
    for (int off = 1; off < 256; off <<= 1) {
        int add = (t >= off) ? sh[t - off] : 0;
        __syncthreads();
        sh[t] += add;
        __syncthreads();
    }
    if (t < nb) bsum[t] = sh[t];
}

// per-node rowp/cursor/dinv; block 0 zeroes sums + Z banks.
__global__ __launch_bounds__(256) void k_rowp(const int* __restrict__ cnt,
                                              const int* __restrict__ bsum,
                                              int* __restrict__ rowp,
                                              int* __restrict__ cursor,
                                              float* __restrict__ dinv,
                                              float* __restrict__ sumsZ, int n) {
    if (blockIdx.x == 0) {
        for (int i = threadIdx.x; i < 4160; i += 256) sumsZ[i] = 0.f;
    }
    __shared__ int sh[256];
    int t = threadIdx.x;
    int i = blockIdx.x * 256 + t;
    int v = (i < n) ? cnt[i] : 0;
    sh[t] = v;
    __syncthreads();
    for (int off = 1; off < 256; off <<= 1) {
        int add = (t >= off) ? sh[t - off] : 0;
        __syncthreads();
        sh[t] += add;
        __syncthreads();
    }
    int base = (blockIdx.x > 0) ? bsum[blockIdx.x - 1] : 0;
    int excl = base + sh[t] - v;
    if (i < n) {
        rowp[i] = excl;
        cursor[i] = excl;
        dinv[i] = 1.0f / sqrtf((float)(v + 1));
        if (i == n - 1) rowp[n] = excl + v;
    }
}

// scatter: one packed 8 B record per edge -> one random line-touch per edge.
__global__ void k_scatter(const int* __restrict__ src, const int* __restrict__ dst,
                          int* __restrict__ cursor, int2* __restrict__ ev,
                          const float* __restrict__ dinv, int ne) {
    int i = blockIdx.x * blockDim.x + threadIdx.x;
    if (i < ne) {
        int d = dst[i], s = src[i];
        int pos = atomicAdd(&cursor[d], 1);
        ev[pos] = make_int2(s, __float_as_int(dinv[s]));
    }
}

// ---------------- GEMM: persistent blocks, fp16 output table ----------------
#define GROWS 32
#define GEMM_BLOCKS 512
__global__ __launch_bounds__(256) void k_gemm(const float* __restrict__ A,
                                              const float* __restrict__ W,
                                              __half* __restrict__ C, int n) {
    __shared__ float sA[GROWS][DD];
    __shared__ float sW[DD][DD];
    int tid = threadIdx.x;

    {
        const float4* Wv = (const float4*)W;
        float4* sWv = (float4*)&sW[0][0];
        for (int i = tid; i < DD * DD / 4; i += 256) sWv[i] = Wv[i];
    }

    int ntiles = (n + GROWS - 1) / GROWS;
    int tx = tid & 31;
    int ty = tid >> 5;
    for (int t = blockIdx.x; t < ntiles; t += gridDim.x) {
        int row0 = t * GROWS;
        __syncthreads();
        {
            const float4* Av = (const float4*)(A + (size_t)row0 * DD);
            float4* sAv = (float4*)&sA[0][0];
            for (int i = tid; i < GROWS * DD / 4; i += 256) {
                int r = i >> 5;
                float4 v = make_float4(0.f, 0.f, 0.f, 0.f);
                if (row0 + r < n) v = Av[i];
                sAv[i] = v;
            }
        }
        __syncthreads();

        float acc[4][4] = {};
        for (int k = 0; k < DD; k += 4) {
            float a[4][4], b[4][4];
            #pragma unroll
            for (int r = 0; r < 4; r++)
                *(float4*)a[r] = *(const float4*)&sA[ty * 4 + r][k];
            #pragma unroll
            for (int kk = 0; kk < 4; kk++)
                *(float4*)b[kk] = *(const float4*)&sW[k + kk][tx * 4];
            #pragma unroll
            for (int r = 0; r < 4; r++)
                #pragma unroll
                for (int kk = 0; kk < 4; kk++)
                    #pragma unroll
                    for (int c = 0; c < 4; c++)
                        acc[r][c] += a[r][kk] * b[kk][c];
        }
        #pragma unroll
        for (int r = 0; r < 4; r++) {
            int row = row0 + ty * 4 + r;
            if (row < n) {
                __half2 p0 = __floats2half2_rn(acc[r][0], acc[r][1]);
                __half2 p1 = __floats2half2_rn(acc[r][2], acc[r][3]);
                uint2 pk;
                pk.x = *(unsigned int*)&p0;
                pk.y = *(unsigned int*)&p1;
                *(uint2*)(C + (size_t)row * DD + tx * 4) = pk;
            }
        }
    }
}

// ---------------- aggregation: one wave/node, fp16 gather, fused BN stats ----------
__global__ __launch_bounds__(256) void k_agg(const __half* __restrict__ h,
                                             const int* __restrict__ rowp,
                                             const int2* __restrict__ ev,
                                             const float* __restrict__ dinv,
                                             const float* __restrict__ bias,
                                             float* __restrict__ out,
                                             float* __restrict__ sums, int n) {
    int tid = threadIdx.x;
    int w = tid >> 6;              // wave 0..3
    int lane = tid & 63;
    int g = lane >> 4;             // edge group 0..3
    int m = lane & 15;             // 16 B chunk within row
    int node = blockIdx.x * 4 + w;
    bool activ = node < n;

    float a[8] = {0.f, 0.f, 0.f, 0.f, 0.f, 0.f, 0.f, 0.f};
    int beg = 0, end = 0;
    if (activ) { beg = rowp[node]; end = rowp[node + 1]; }
    #pragma unroll 4
    for (int e = beg + g; e < end; e += 4) {
        int2 r = ev[e];
        int s = r.x;
        float ww = __int_as_float(r.y);
        float4 raw = *(const float4*)(h + (size_t)s * DD + m * 8);
        const __half2* hp = (const __half2*)&raw;
        float2 c0 = __half22float2(hp[0]);
        float2 c1 = __half22float2(hp[1]);
        float2 c2 = __half22float2(hp[2]);
        float2 c3 = __half22float2(hp[3]);
        a[0] += ww * c0.x; a[1] += ww * c0.y;
        a[2] += ww * c1.x; a[3] += ww * c1.y;
        a[4] += ww * c2.x; a[5] += ww * c2.y;
        a[6] += ww * c3.x; a[7] += ww * c3.y;
    }
    #pragma unroll
    for (int j = 0; j < 8; j++) {
        a[j] += __shfl_xor(a[j], 16);
        a[j] += __shfl_xor(a[j], 32);
    }
    float o[8] = {0.f, 0.f, 0.f, 0.f, 0.f, 0.f, 0.f, 0.f};
    if (activ && lane < 16) {
        float di = dinv[node], dii = di * di;
        float4 raw = *(const float4*)(h + (size_t)node * DD + m * 8);
        const __half2* hp = (const __half2*)&raw;
        float2 s0 = __half22float2(hp[0]);
        float2 s1 = __half22float2(hp[1]);
        float2 s2 = __half22float2(hp[2]);
        float2 s3 = __half22float2(hp[3]);
        float sf[8] = {s0.x, s0.y, s1.x, s1.y, s2.x, s2.y, s3.x, s3.y};
        float4 b0 = *(const float4*)(bias + m * 8);
        float4 b1 = *(const float4*)(bias + m * 8 + 4);
        float bf[8] = {b0.x, b0.y, b0.z, b0.w, b1.x, b1.y, b1.z, b1.w};
        #pragma unroll
        for (int j = 0; j < 8; j++)
            o[j] = di * a[j] + dii * sf[j] + bf[j];
        float* op = out + (size_t)node * DD + m * 8;
        *(float4*)op = make_float4(o[0], o[1], o[2], o[3]);
        *(float4*)(op + 4) = make_float4(o[4], o[5], o[6], o[7]);
    }
    __shared__ float rs[4][128];
    __shared__ float rq[4][128];
    if (lane < 16) {
        #pragma unroll
        for (int j = 0; j < 8; j++) {
            rs[w][m * 8 + j] = o[j];
            rq[w][m * 8 + j] = o[j] * o[j];
        }
    }
    __syncthreads();
    int bank = blockIdx.x & 7;
    if (tid < 128) {
        float s = rs[0][tid] + rs[1][tid] + rs[2][tid] + rs[3][tid];
        atomicAdd(&sums[bank * 256 + tid], s);
    } else {
        int t = tid - 128;
        float q = rq[0][t] + rq[1][t] + rq[2][t] + rq[3][t];
        atomicAdd(&sums[bank * 256 + 128 + t], q);
    }
}

// ---------------- BN apply + ReLU + residual, optional fused attention score --------
__global__ __launch_bounds__(256) void k_bn(const float* __restrict__ X,
                                            const float* __restrict__ res,
                                            const float* __restrict__ sums,
                                            const float* __restrict__ gamma,
                                            const float* __restrict__ beta,
                                            const float* __restrict__ Wa,
                                            const float* __restrict__ ba,
                                            float* __restrict__ out,
                                            float* __restrict__ evec,
                                            float* __restrict__ Zb, int n) {
    __shared__ float s_scale[128], s_shift[128];
    if (threadIdx.x < 128) {
        int ff = threadIdx.x;
        float ssum = 0.f, qsum = 0.f;
        #pragma unroll
        for (int b = 0; b < 8; b++) {
            ssum += sums[b * 256 + ff];
            qsum += sums[b * 256 + 128 + ff];
        }
        float inv_n = 1.0f / (float)n;
        float mean = ssum * inv_n;
        float var = qsum * inv_n - mean * mean;
        float sc = gamma[ff] * (1.0f / sqrtf(var + BN_EPS));
        s_scale[ff] = sc;
        s_shift[ff] = beta[ff] - mean * sc;
    }
    __syncthreads();
    int idx = blockIdx.x * 256 + threadIdx.x;
    int total = n * (DD / 4);
    int f = (threadIdx.x & 31) * 4;
    float o[4] = {0.f, 0.f, 0.f, 0.f};
    if (idx < total) {
        float4 v = ((const float4*)X)[idx];
        float4 rv = ((const float4*)res)[idx];
        float vi[4] = {v.x, v.y, v.z, v.w};
        float ri[4] = {rv.x, rv.y, rv.z, rv.w};
        #pragma unroll
        for (int j = 0; j < 4; j++) {
            float x = vi[j] * s_scale[f + j] + s_shift[f + j];
            x = fmaxf(x, 0.f);
            o[j] = x + ri[j];
        }
        ((float4*)out)[idx] = make_float4(o[0], o[1], o[2], o[3]);
    }
    if (Wa != nullptr) {
        float t = 0.f;
        if (idx < total) {
            float4 wv = *(const float4*)(Wa + f);
            t = o[0] * wv.x + o[1] * wv.y + o[2] * wv.z + o[3] * wv.w;
        }
        #pragma unroll
        for (int m = 16; m >= 1; m >>= 1) t += __shfl_xor(t, m);
        __shared__ float part[8];
        if ((threadIdx.x & 31) == 0) {
            float ev = 0.f;
            if (idx < total) {
                ev = expf(tanhf(t + ba[0]));
                evec[idx >> 5] = ev;
            }
            part[threadIdx.x >> 5] = ev;
        }
        __syncthreads();
        if (threadIdx.x == 0) {
            float z = part[0] + part[1] + part[2] + part[3] +
                      part[4] + part[5] + part[6] + part[7];
            atomicAdd(&Zb[blockIdx.x & 63], z);
        }
    }
}

// ---------------- final: out = h * e / Z (Z from 64 banks) ----------------
__global__ __launch_bounds__(256) void k_out(const float* __restrict__ H,
                                             const float* __restrict__ evec,
                                             const float* __restrict__ Zb,
                                             float* __restrict__ out, int n) {
    __shared__ float sZ;
    if (threadIdx.x == 0) {
        float z = 0.f;
        #pragma unroll
        for (int i = 0; i < 64; i++) z += Zb[i];
        sZ = z;
    }
    __syncthreads();
    int idx = blockIdx.x * blockDim.x + threadIdx.x;
    int total = n * (DD / 4);
    if (idx >= total) return;
    int node = idx >> 5;
    float s = evec[node] / sZ;
    float4 h = ((const float4*)H)[idx];
    ((float4*)out)[idx] = make_float4(h.x * s, h.y * s, h.z * s, h.w * s);
}

extern "C" void kernel_launch(void* const* d_in, const int* in_sizes, int n_in,
                              void* d_out, int out_size, void* d_ws, size_t ws_size,
                              hipStream_t stream) {
    const float* x   = (const float*)d_in[0];
    const int* eidx  = (const int*)d_in[1];
    const float* W1  = (const float*)d_in[2];
    const float* b1  = (const float*)d_in[3];
    const float* g1  = (const float*)d_in[4];
    const float* be1 = (const float*)d_in[5];
    const float* W2  = (const float*)d_in[6];
    const float* b2  = (const float*)d_in[7];
    const float* g2  = (const float*)d_in[8];
    const float* be2 = (const float*)d_in[9];
    const float* Wa  = (const float*)d_in[10];
    const float* ba  = (const float*)d_in[11];
    float* out = (float*)d_out;

    const int* srcp = eidx;
    const int* dstp = eidx + NE;

    float* bufA = (float*)d_ws;              // N*D region; fp16 gather table
    float* bufB = bufA + (size_t)NN * DD;    // N*D (agg out)
    float* bufC = bufB + (size_t)NN * DD;    // N*D (h1 / h2)
    int2* ev    = (int2*)(bufC + (size_t)NN * DD);   // NE packed edge records
    float* dinv = (float*)(ev + NE);         // NN
    float* evec = dinv + NN;                 // NN
    float* sums = evec + NN;                 // 2 layers x 8 banks x 256 = 4096
    float* Zb   = sums + 4096;               // 64 banks
    int* cnt    = (int*)(Zb + 64);           // NN
    int* rowp   = cnt + NN;                  // NN+1 (pad 64)
    int* cursor = rowp + NN + 64;            // NN
    int* bsum   = cursor + NN;               // 256

    __half* hH  = (__half*)bufA;             // fp16 gather table, 12.8 MB

    float* sumsL1 = sums;
    float* sumsL2 = sums + 2048;

    const int nscan = (NN + 255) / 256;      // 196 blocks

    // ---- CSR build (k_rowp block 0 zeroes sums+Zb) ----
    hipMemsetAsync(cnt, 0, (size_t)NN * sizeof(int), stream);
    k_hist<<<(NE + 255) / 256, 256, 0, stream>>>(dstp, cnt, NE);
    k_bsum<<<nscan, 256, 0, stream>>>(cnt, bsum, NN);
    k_bscan<<<1, 256, 0, stream>>>(bsum, nscan);
    k_rowp<<<nscan, 256, 0, stream>>>(cnt, bsum, rowp, cursor, dinv, sums, NN);
    k_scatter<<<(NE + 255) / 256, 256, 0, stream>>>(srcp, dstp, cursor, ev, dinv, NE);

    int agg_grid  = (NN + 3) / 4;                    // 12500
    int ew_grid   = (NN * (DD / 4) + 255) / 256;     // 6250

    // ---- layer 1 ----
    k_gemm<<<GEMM_BLOCKS, 256, 0, stream>>>(x, W1, hH, NN);
    k_agg<<<agg_grid, 256, 0, stream>>>(hH, rowp, ev, dinv, b1, bufB, sumsL1, NN);
    k_bn<<<ew_grid, 256, 0, stream>>>(bufB, x, sumsL1, g1, be1, nullptr, nullptr,
                                      bufC, nullptr, nullptr, NN);

    // ---- layer 2 ----
    k_gemm<<<GEMM_BLOCKS, 256, 0, stream>>>(bufC, W2, hH, NN);
    k_agg<<<agg_grid, 256, 0, stream>>>(hH, rowp, ev, dinv, b2, bufB, sumsL2, NN);
    k_bn<<<ew_grid, 256, 0, stream>>>(bufB, bufC, sumsL2, g2, be2, Wa, ba,
                                      bufC, evec, Zb, NN);   // in-place res ok

    // ---- output ----
    k_out<<<ew_grid, 256, 0, stream>>>(bufC, evec, Zb, out, NN);
}

// Round 12
// 396.913 us; speedup vs baseline: 1.4080x; 1.0237x over previous
//
#include <hip/hip_runtime.h>
#include <hip/hip_fp16.h>

#define NN 50000
#define DD 128
#define NE 800000
#define BN_EPS 1e-5f

// ---------------- CSR build ----------------
__global__ void k_hist(const int* __restrict__ dst, int* __restrict__ cnt, int ne) {
    int i = blockIdx.x * blockDim.x + threadIdx.x;
    if (i < ne) atomicAdd(&cnt[dst[i]], 1);
}

__global__ __launch_bounds__(256) void k_bsum(const int* __restrict__ cnt,
                                              int* __restrict__ bsum, int n) {
    __shared__ int red[256];
    int i = blockIdx.x * 256 + threadIdx.x;
    int v = (i < n) ? cnt[i] : 0;
    red[threadIdx.x] = v;
    __syncthreads();
    for (int off = 128; off > 0; off >>= 1) {
        if (threadIdx.x < off) red[threadIdx.x] += red[threadIdx.x + off];
        __syncthreads();
    }
    if (threadIdx.x == 0) bsum[blockIdx.x] = red[0];
}

__global__ __launch_bounds__(256) void k_bscan(int* __restrict__ bsum, int nb) {
    __shared__ int sh[256];
    int t = threadIdx.x;
    sh[t] = (t < nb) ? bsum[t] : 0;
    __syncthreads();
    for (int off = 1; off < 256; off <<= 1) {
        int add = (t >= off) ? sh[t - off] : 0;
        __syncthreads();
        sh[t] += add;
        __syncthreads();
    }
    if (t < nb) bsum[t] = sh[t];
}

// per-node rowp/cursor/dinv; block 0 zeroes sums + Z banks.
__global__ __launch_bounds__(256) void k_rowp(const int* __restrict__ cnt,
                                              const int* __restrict__ bsum,
                                              int* __restrict__ rowp,
                                              int* __restrict__ cursor,
                                              float* __restrict__ dinv,
                                              float* __restrict__ sumsZ, int n) {
    if (blockIdx.x == 0) {
        for (int i = threadIdx.x; i < 4160; i += 256) sumsZ[i] = 0.f;
    }
    __shared__ int sh[256];
    int t = threadIdx.x;
    int i = blockIdx.x * 256 + t;
    int v = (i < n) ? cnt[i] : 0;
    sh[t] = v;
    __syncthreads();
    for (int off = 1; off < 256; off <<= 1) {
        int add = (t >= off) ? sh[t - off] : 0;
        __syncthreads();
        sh[t] += add;
        __syncthreads();
    }
    int base = (blockIdx.x > 0) ? bsum[blockIdx.x - 1] : 0;
    int excl = base + sh[t] - v;
    if (i < n) {
        rowp[i] = excl;
        cursor[i] = excl;
        dinv[i] = 1.0f / sqrtf((float)(v + 1));
        if (i == n - 1) rowp[n] = excl + v;
    }
}

// scatter: one packed 4 B record per edge (src in low 16 bits, fp16 dinv[src]
// in high 16) -> halves the replicated partial-line writeback traffic.
__global__ void k_scatter(const int* __restrict__ src, const int* __restrict__ dst,
                          int* __restrict__ cursor, unsigned* __restrict__ ev,
                          const float* __restrict__ dinv, int ne) {
    int i = blockIdx.x * blockDim.x + threadIdx.x;
    if (i < ne) {
        int d = dst[i], s = src[i];
        int pos = atomicAdd(&cursor[d], 1);
        unsigned short hv = __half_as_ushort(__float2half_rn(dinv[s]));
        ev[pos] = (unsigned)s | ((unsigned)hv << 16);
    }
}

// ---------------- GEMM: persistent blocks, fp16 output table ----------------
#define GROWS 32
#define GEMM_BLOCKS 512
__global__ __launch_bounds__(256) void k_gemm(const float* __restrict__ A,
                                              const float* __restrict__ W,
                                              __half* __restrict__ C, int n) {
    __shared__ float sA[GROWS][DD];
    __shared__ float sW[DD][DD];
    int tid = threadIdx.x;

    {
        const float4* Wv = (const float4*)W;
        float4* sWv = (float4*)&sW[0][0];
        for (int i = tid; i < DD * DD / 4; i += 256) sWv[i] = Wv[i];
    }

    int ntiles = (n + GROWS - 1) / GROWS;
    int tx = tid & 31;
    int ty = tid >> 5;
    for (int t = blockIdx.x; t < ntiles; t += gridDim.x) {
        int row0 = t * GROWS;
        __syncthreads();
        {
            const float4* Av = (const float4*)(A + (size_t)row0 * DD);
            float4* sAv = (float4*)&sA[0][0];
            for (int i = tid; i < GROWS * DD / 4; i += 256) {
                int r = i >> 5;
                float4 v = make_float4(0.f, 0.f, 0.f, 0.f);
                if (row0 + r < n) v = Av[i];
                sAv[i] = v;
            }
        }
        __syncthreads();

        float acc[4][4] = {};
        for (int k = 0; k < DD; k += 4) {
            float a[4][4], b[4][4];
            #pragma unroll
            for (int r = 0; r < 4; r++)
                *(float4*)a[r] = *(const float4*)&sA[ty * 4 + r][k];
            #pragma unroll
            for (int kk = 0; kk < 4; kk++)
                *(float4*)b[kk] = *(const float4*)&sW[k + kk][tx * 4];
            #pragma unroll
            for (int r = 0; r < 4; r++)
                #pragma unroll
                for (int kk = 0; kk < 4; kk++)
                    #pragma unroll
                    for (int c = 0; c < 4; c++)
                        acc[r][c] += a[r][kk] * b[kk][c];
        }
        #pragma unroll
        for (int r = 0; r < 4; r++) {
            int row = row0 + ty * 4 + r;
            if (row < n) {
                __half2 p0 = __floats2half2_rn(acc[r][0], acc[r][1]);
                __half2 p1 = __floats2half2_rn(acc[r][2], acc[r][3]);
                uint2 pk;
                pk.x = *(unsigned int*)&p0;
                pk.y = *(unsigned int*)&p1;
                *(uint2*)(C + (size_t)row * DD + tx * 4) = pk;
            }
        }
    }
}

// ---------------- aggregation: one wave/node, fp16 gather, fused BN stats ----------
__global__ __launch_bounds__(256) void k_agg(const __half* __restrict__ h,
                                             const int* __restrict__ rowp,
                                             const unsigned* __restrict__ ev,
                                             const float* __restrict__ dinv,
                                             const float* __restrict__ bias,
                                             float* __restrict__ out,
                                             float* __restrict__ sums, int n) {
    int tid = threadIdx.x;
    int w = tid >> 6;              // wave 0..3
    int lane = tid & 63;
    int g = lane >> 4;             // edge group 0..3
    int m = lane & 15;             // 16 B chunk within row
    int node = blockIdx.x * 4 + w;
    bool activ = node < n;

    float a[8] = {0.f, 0.f, 0.f, 0.f, 0.f, 0.f, 0.f, 0.f};
    int beg = 0, end = 0;
    if (activ) { beg = rowp[node]; end = rowp[node + 1]; }
    #pragma unroll 4
    for (int e = beg + g; e < end; e += 4) {
        unsigned r = ev[e];
        int s = r & 0xFFFF;
        float ww = __half2float(__ushort_as_half((unsigned short)(r >> 16)));
        float4 raw = *(const float4*)(h + (size_t)s * DD + m * 8);
        const __half2* hp = (const __half2*)&raw;
        float2 c0 = __half22float2(hp[0]);
        float2 c1 = __half22float2(hp[1]);
        float2 c2 = __half22float2(hp[2]);
        float2 c3 = __half22float2(hp[3]);
        a[0] += ww * c0.x; a[1] += ww * c0.y;
        a[2] += ww * c1.x; a[3] += ww * c1.y;
        a[4] += ww * c2.x; a[5] += ww * c2.y;
        a[6] += ww * c3.x; a[7] += ww * c3.y;
    }
    #pragma unroll
    for (int j = 0; j < 8; j++) {
        a[j] += __shfl_xor(a[j], 16);
        a[j] += __shfl_xor(a[j], 32);
    }
    float o[8] = {0.f, 0.f, 0.f, 0.f, 0.f, 0.f, 0.f, 0.f};
    if (activ && lane < 16) {
        float di = dinv[node], dii = di * di;
        float4 raw = *(const float4*)(h + (size_t)node * DD + m * 8);
        const __half2* hp = (const __half2*)&raw;
        float2 s0 = __half22float2(hp[0]);
        float2 s1 = __half22float2(hp[1]);
        float2 s2 = __half22float2(hp[2]);
        float2 s3 = __half22float2(hp[3]);
        float sf[8] = {s0.x, s0.y, s1.x, s1.y, s2.x, s2.y, s3.x, s3.y};
        float4 b0 = *(const float4*)(bias + m * 8);
        float4 b1 = *(const float4*)(bias + m * 8 + 4);
        float bf[8] = {b0.x, b0.y, b0.z, b0.w, b1.x, b1.y, b1.z, b1.w};
        #pragma unroll
        for (int j = 0; j < 8; j++)
            o[j] = di * a[j] + dii * sf[j] + bf[j];
        float* op = out + (size_t)node * DD + m * 8;
        *(float4*)op = make_float4(o[0], o[1], o[2], o[3]);
        *(float4*)(op + 4) = make_float4(o[4], o[5], o[6], o[7]);
    }
    __shared__ float rs[4][128];
    __shared__ float rq[4][128];
    if (lane < 16) {
        #pragma unroll
        for (int j = 0; j < 8; j++) {
            rs[w][m * 8 + j] = o[j];
            rq[w][m * 8 + j] = o[j] * o[j];
        }
    }
    __syncthreads();
    int bank = blockIdx.x & 7;
    if (tid < 128) {
        float s = rs[0][tid] + rs[1][tid] + rs[2][tid] + rs[3][tid];
        atomicAdd(&sums[bank * 256 + tid], s);
    } else {
        int t = tid - 128;
        float q = rq[0][t] + rq[1][t] + rq[2][t] + rq[3][t];
        atomicAdd(&sums[bank * 256 + 128 + t], q);
    }
}

// ---------------- BN apply + ReLU + residual, optional fused attention score --------
__global__ __launch_bounds__(256) void k_bn(const float* __restrict__ X,
                                            const float* __restrict__ res,
                                            const float* __restrict__ sums,
                                            const float* __restrict__ gamma,
                                            const float* __restrict__ beta,
                                            const float* __restrict__ Wa,
                                            const float* __restrict__ ba,
                                            float* __restrict__ out,
                                            float* __restrict__ evec,
                                            float* __restrict__ Zb, int n) {
    __shared__ float s_scale[128], s_shift[128];
    if (threadIdx.x < 128) {
        int ff = threadIdx.x;
        float ssum = 0.f, qsum = 0.f;
        #pragma unroll
        for (int b = 0; b < 8; b++) {
            ssum += sums[b * 256 + ff];
            qsum += sums[b * 256 + 128 + ff];
        }
        float inv_n = 1.0f / (float)n;
        float mean = ssum * inv_n;
        float var = qsum * inv_n - mean * mean;
        float sc = gamma[ff] * (1.0f / sqrtf(var + BN_EPS));
        s_scale[ff] = sc;
        s_shift[ff] = beta[ff] - mean * sc;
    }
    __syncthreads();
    int idx = blockIdx.x * 256 + threadIdx.x;
    int total = n * (DD / 4);
    int f = (threadIdx.x & 31) * 4;
    float o[4] = {0.f, 0.f, 0.f, 0.f};
    if (idx < total) {
        float4 v = ((const float4*)X)[idx];
        float4 rv = ((const float4*)res)[idx];
        float vi[4] = {v.x, v.y, v.z, v.w};
        float ri[4] = {rv.x, rv.y, rv.z, rv.w};
        #pragma unroll
        for (int j = 0; j < 4; j++) {
            float x = vi[j] * s_scale[f + j] + s_shift[f + j];
            x = fmaxf(x, 0.f);
            o[j] = x + ri[j];
        }
        ((float4*)out)[idx] = make_float4(o[0], o[1], o[2], o[3]);
    }
    if (Wa != nullptr) {
        float t = 0.f;
        if (idx < total) {
            float4 wv = *(const float4*)(Wa + f);
            t = o[0] * wv.x + o[1] * wv.y + o[2] * wv.z + o[3] * wv.w;
        }
        #pragma unroll
        for (int m = 16; m >= 1; m >>= 1) t += __shfl_xor(t, m);
        __shared__ float part[8];
        if ((threadIdx.x & 31) == 0) {
            float ev = 0.f;
            if (idx < total) {
                ev = expf(tanhf(t + ba[0]));
                evec[idx >> 5] = ev;
            }
            part[threadIdx.x >> 5] = ev;
        }
        __syncthreads();
        if (threadIdx.x == 0) {
            float z = part[0] + part[1] + part[2] + part[3] +
                      part[4] + part[5] + part[6] + part[7];
            atomicAdd(&Zb[blockIdx.x & 63], z);
        }
    }
}

// ---------------- final: out = h * e / Z (Z from 64 banks) ----------------
__global__ __launch_bounds__(256) void k_out(const float* __restrict__ H,
                                             const float* __restrict__ evec,
                                             const float* __restrict__ Zb,
                                             float* __restrict__ out, int n) {
    __shared__ float sZ;
    if (threadIdx.x == 0) {
        float z = 0.f;
        #pragma unroll
        for (int i = 0; i < 64; i++) z += Zb[i];
        sZ = z;
    }
    __syncthreads();
    int idx = blockIdx.x * blockDim.x + threadIdx.x;
    int total = n * (DD / 4);
    if (idx >= total) return;
    int node = idx >> 5;
    float s = evec[node] / sZ;
    float4 h = ((const float4*)H)[idx];
    ((float4*)out)[idx] = make_float4(h.x * s, h.y * s, h.z * s, h.w * s);
}

extern "C" void kernel_launch(void* const* d_in, const int* in_sizes, int n_in,
                              void* d_out, int out_size, void* d_ws, size_t ws_size,
                              hipStream_t stream) {
    const float* x   = (const float*)d_in[0];
    const int* eidx  = (const int*)d_in[1];
    const float* W1  = (const float*)d_in[2];
    const float* b1  = (const float*)d_in[3];
    const float* g1  = (const float*)d_in[4];
    const float* be1 = (const float*)d_in[5];
    const float* W2  = (const float*)d_in[6];
    const float* b2  = (const float*)d_in[7];
    const float* g2  = (const float*)d_in[8];
    const float* be2 = (const float*)d_in[9];
    const float* Wa  = (const float*)d_in[10];
    const float* ba  = (const float*)d_in[11];
    float* out = (float*)d_out;

    const int* srcp = eidx;
    const int* dstp = eidx + NE;

    float* bufA = (float*)d_ws;              // N*D region; fp16 gather table
    float* bufB = bufA + (size_t)NN * DD;    // N*D (agg out)
    float* bufC = bufB + (size_t)NN * DD;    // N*D (h1 / h2)
    unsigned* ev = (unsigned*)(bufC + (size_t)NN * DD);   // NE packed 4B records
    float* dinv = (float*)(ev + NE);         // NN
    float* evec = dinv + NN;                 // NN
    float* sums = evec + NN;                 // 2 layers x 8 banks x 256 = 4096
    float* Zb   = sums + 4096;               // 64 banks
    int* cnt    = (int*)(Zb + 64);           // NN
    int* rowp   = cnt + NN;                  // NN+1 (pad 64)
    int* cursor = rowp + NN + 64;            // NN
    int* bsum   = cursor + NN;               // 256

    __half* hH  = (__half*)bufA;             // fp16 gather table, 12.8 MB

    float* sumsL1 = sums;
    float* sumsL2 = sums + 2048;

    const int nscan = (NN + 255) / 256;      // 196 blocks

    // ---- CSR build (k_rowp block 0 zeroes sums+Zb) ----
    hipMemsetAsync(cnt, 0, (size_t)NN * sizeof(int), stream);
    k_hist<<<(NE + 255) / 256, 256, 0, stream>>>(dstp, cnt, NE);
    k_bsum<<<nscan, 256, 0, stream>>>(cnt, bsum, NN);
    k_bscan<<<1, 256, 0, stream>>>(bsum, nscan);
    k_rowp<<<nscan, 256, 0, stream>>>(cnt, bsum, rowp, cursor, dinv, sums, NN);
    k_scatter<<<(NE + 255) / 256, 256, 0, stream>>>(srcp, dstp, cursor, ev, dinv, NE);

    int agg_grid  = (NN + 3) / 4;                    // 12500
    int ew_grid   = (NN * (DD / 4) + 255) / 256;     // 6250

    // ---- layer 1 ----
    k_gemm<<<GEMM_BLOCKS, 256, 0, stream>>>(x, W1, hH, NN);
    k_agg<<<agg_grid, 256, 0, stream>>>(hH, rowp, ev, dinv, b1, bufB, sumsL1, NN);
    k_bn<<<ew_grid, 256, 0, stream>>>(bufB, x, sumsL1, g1, be1, nullptr, nullptr,
                                      bufC, nullptr, nullptr, NN);

    // ---- layer 2 ----
    k_gemm<<<GEMM_BLOCKS, 256, 0, stream>>>(bufC, W2, hH, NN);
    k_agg<<<agg_grid, 256, 0, stream>>>(hH, rowp, ev, dinv, b2, bufB, sumsL2, NN);
    k_bn<<<ew_grid, 256, 0, stream>>>(bufB, bufC, sumsL2, g2, be2, Wa, ba,
                                      bufC, evec, Zb, NN);   // in-place res ok

    // ---- output ----
    k_out<<<ew_grid, 256, 0, stream>>>(bufC, evec, Zb, out, NN);
}